// Round 1
// baseline (826.383 us; speedup 1.0000x reference)
//
#include <hip/hip_runtime.h>
#include <hip/hip_bf16.h>

typedef unsigned int uint;
typedef unsigned short ushort;

#define N_NODES 60000
#define N_EDGES 600000
#define NREL 7
#define D_IN 64
#define DHID 128
#define D2 64
#define LEPS 1e-5f

__device__ __forceinline__ float bf2f(uint u16) {
    return __uint_as_float(u16 << 16);
}
__device__ __forceinline__ uint f2bf(float f) {
    uint u = __float_as_uint(f);
    uint lsb = (u >> 16) & 1u;
    u += 0x7fffu + lsb;
    return u >> 16;
}
__device__ __forceinline__ uint pack2(float a, float b) {
    return f2bf(a) | (f2bf(b) << 16);
}

// ---------------- embedding: h0 = clip(x,-10,10) @ emb_W + emb_b (bf16 out) ----
__global__ __launch_bounds__(256) void k_embed(const float* __restrict__ x,
                                               const float* __restrict__ W,
                                               const float* __restrict__ bias,
                                               ushort* __restrict__ h) {
    __shared__ float Ws[D_IN * DHID];   // 32 KB
    __shared__ float xs[2][D_IN];
    __shared__ float brow[DHID];
    for (int i = threadIdx.x; i < D_IN * DHID; i += 256) Ws[i] = W[i];
    for (int i = threadIdx.x; i < DHID; i += 256) brow[i] = bias[i];
    const int g = threadIdx.x >> 7;      // node slot 0/1 in block
    const int c = threadIdx.x & 127;     // output column
    const int nb = gridDim.x;
    const int iters = (N_NODES + nb * 2 - 1) / (nb * 2);
    for (int it = 0; it < iters; ++it) {
        const int n = (it * nb + blockIdx.x) * 2 + g;
        __syncthreads();
        if (n < N_NODES && c < D_IN) {
            float v = x[(size_t)n * D_IN + c];
            xs[g][c] = fminf(fmaxf(v, -10.f), 10.f);
        }
        __syncthreads();
        if (n < N_NODES) {
            float acc = brow[c];
            #pragma unroll
            for (int k = 0; k < D_IN; ++k) acc = fmaf(xs[g][k], Ws[k * DHID + c], acc);
            h[(size_t)n * DHID + c] = (ushort)f2bf(acc);
        }
    }
}

// ---------------- CSR build ----------------
__global__ void k_zero2(int* __restrict__ a, int* __restrict__ b) {
    int i = blockIdx.x * 256 + threadIdx.x;
    if (i < N_NODES) { a[i] = 0; b[i] = 0; }
}
__global__ void k_deg(const int* __restrict__ dst, int* __restrict__ deg) {
    for (int e = blockIdx.x * 256 + threadIdx.x; e < N_EDGES; e += gridDim.x * 256)
        atomicAdd(&deg[dst[e]], 1);
}
__global__ void k_scan1(const int* __restrict__ deg, int* __restrict__ rp, int* __restrict__ bs) {
    __shared__ int s[256];
    const int t = threadIdx.x;
    const int i = blockIdx.x * 256 + t;
    const int v = (i < N_NODES) ? deg[i] : 0;
    s[t] = v;
    __syncthreads();
    for (int o = 1; o < 256; o <<= 1) {
        int u = (t >= o) ? s[t - o] : 0;
        __syncthreads();
        s[t] += u;
        __syncthreads();
    }
    if (i < N_NODES) rp[i] = s[t] - v;   // exclusive within block
    if (t == 255) bs[blockIdx.x] = s[255];
}
__global__ void k_scan2(int* __restrict__ bs, int nb) {
    __shared__ int s[256];
    const int t = threadIdx.x;
    const int v = (t < nb) ? bs[t] : 0;
    s[t] = v;
    __syncthreads();
    for (int o = 1; o < 256; o <<= 1) {
        int u = (t >= o) ? s[t - o] : 0;
        __syncthreads();
        s[t] += u;
        __syncthreads();
    }
    if (t < nb) bs[t] = s[t] - v;        // exclusive
}
__global__ void k_scanadd(int* __restrict__ rp, const int* __restrict__ bs) {
    const int i = blockIdx.x * 256 + threadIdx.x;
    if (i < N_NODES) rp[i] += bs[blockIdx.x];
    if (blockIdx.x == 0 && threadIdx.x == 0) rp[N_NODES] = N_EDGES;
}
__global__ void k_scatter(const int* __restrict__ src, const int* __restrict__ dst,
                          const int* __restrict__ et, const int* __restrict__ rp,
                          int* __restrict__ fill, int* __restrict__ csr) {
    for (int e = blockIdx.x * 256 + threadIdx.x; e < N_EDGES; e += gridDim.x * 256) {
        const int d = dst[e];
        const int p = rp[d] + atomicAdd(&fill[d], 1);
        csr[p] = src[e] | (et[e] << 16);   // src < 65536, type < 8
    }
}

// ---------------- aggregation: M[n][r*128+d] = mean over type-r in-edges of h[src][d]
// one wave per dst node; lane holds features 2*lane, 2*lane+1
__global__ __launch_bounds__(256) void k_agg(const uint* __restrict__ h32,
                                             const int* __restrict__ rp,
                                             const int* __restrict__ csr,
                                             uint* __restrict__ M32) {
    const int wave = (blockIdx.x * 256 + threadIdx.x) >> 6;
    const int lane = threadIdx.x & 63;
    const int nwaves = gridDim.x * 4;
    for (int n = wave; n < N_NODES; n += nwaves) {
        float a0[NREL], a1[NREL], cf[NREL];
        #pragma unroll
        for (int r = 0; r < NREL; ++r) { a0[r] = 0.f; a1[r] = 0.f; cf[r] = 0.f; }
        const int beg = rp[n], end = rp[n + 1];
        for (int e = beg; e < end; ++e) {
            const int ent = __builtin_amdgcn_readfirstlane(csr[e]);  // wave-uniform
            const int s = ent & 0xFFFF;
            const int r = ent >> 16;
            const uint hv = h32[(size_t)s * 64 + lane];
            const float v0 = bf2f(hv & 0xFFFFu);
            const float v1 = bf2f(hv >> 16);
            switch (r) {
                case 0: a0[0] += v0; a1[0] += v1; cf[0] += 1.f; break;
                case 1: a0[1] += v0; a1[1] += v1; cf[1] += 1.f; break;
                case 2: a0[2] += v0; a1[2] += v1; cf[2] += 1.f; break;
                case 3: a0[3] += v0; a1[3] += v1; cf[3] += 1.f; break;
                case 4: a0[4] += v0; a1[4] += v1; cf[4] += 1.f; break;
                case 5: a0[5] += v0; a1[5] += v1; cf[5] += 1.f; break;
                default: a0[6] += v0; a1[6] += v1; cf[6] += 1.f; break;
            }
        }
        const size_t base = (size_t)n * 448 + lane;
        #pragma unroll
        for (int r = 0; r < NREL; ++r) {
            const float sc = 1.f / fmaxf(cf[r], 1.f);
            M32[base + r * 64] = pack2(a0[r] * sc, a1[r] * sc);
        }
    }
}

// ---------------- fused GEMM + LayerNorm + ReLU ----------------
// C[n][j] = sum_k896 M[n][k]*B1[k][j] + sum_k128 h[n][k]*B2[k][j] + bias[j]
// then LN over j (128) with g/bb, ReLU, store bf16.
__global__ __launch_bounds__(256) void k_gemm_ln(const uint* __restrict__ A1,   // M bf16 dwords, stride 448
                                                 const uint* __restrict__ A2,   // h bf16 dwords, stride 64
                                                 const float* __restrict__ B1,  // 896x128
                                                 const float* __restrict__ B2,  // 128x128
                                                 const float* __restrict__ bias,
                                                 const float* __restrict__ g,
                                                 const float* __restrict__ bb,
                                                 uint* __restrict__ out,        // bf16 dwords, stride 64
                                                 int nrows) {
    __shared__ float As[128][33];
    __shared__ float Bs[32][128];
    const int tid = threadIdx.x;
    const int tx = tid & 15;     // column group: cols tx*8 .. tx*8+7
    const int ty = tid >> 4;     // row group: rows ty + 16*m
    const int row0 = blockIdx.x * 128;

    float bv[8], gv[8], bbv[8];
    #pragma unroll
    for (int c = 0; c < 8; ++c) {
        const int col = tx * 8 + c;
        bv[c] = bias[col]; gv[c] = g[col]; bbv[c] = bb[col];
    }
    float acc[8][8];
    #pragma unroll
    for (int m = 0; m < 8; ++m)
        #pragma unroll
        for (int c = 0; c < 8; ++c) acc[m][c] = bv[c];

    const int arow = tid >> 1;   // 0..127
    const int ahalf = tid & 1;   // which 16-elem half of the 32-wide k-chunk
    const int rg = row0 + arow;
    const bool rok = rg < nrows;

    for (int ch = 0; ch < 32; ++ch) {
        const int k0 = ch * 32;
        __syncthreads();
        // stage A chunk (128 rows x 32 k, bf16 -> f32)
        {
            uint d[8];
            if (rok) {
                const uint* p;
                if (k0 < 896) p = A1 + (size_t)rg * 448 + (k0 >> 1) + ahalf * 8;
                else          p = A2 + (size_t)rg * 64 + ((k0 - 896) >> 1) + ahalf * 8;
                const uint4 q0 = *(const uint4*)p;
                const uint4 q1 = *(const uint4*)(p + 4);
                d[0] = q0.x; d[1] = q0.y; d[2] = q0.z; d[3] = q0.w;
                d[4] = q1.x; d[5] = q1.y; d[6] = q1.z; d[7] = q1.w;
            } else {
                #pragma unroll
                for (int i = 0; i < 8; ++i) d[i] = 0;
            }
            #pragma unroll
            for (int i = 0; i < 8; ++i) {
                As[arow][ahalf * 16 + 2 * i]     = bf2f(d[i] & 0xFFFFu);
                As[arow][ahalf * 16 + 2 * i + 1] = bf2f(d[i] >> 16);
            }
        }
        // stage B chunk (32 k x 128 cols, f32)
        {
            const float* Bp = (k0 < 896) ? (B1 + (size_t)k0 * 128) : (B2 + (size_t)(k0 - 896) * 128);
            #pragma unroll
            for (int i = 0; i < 4; ++i) {
                const int s = tid + i * 256;
                const int k = s >> 5, j4 = s & 31;
                const float4 v = *(const float4*)(Bp + k * 128 + j4 * 4);
                *(float4*)&Bs[k][j4 * 4] = v;
            }
        }
        __syncthreads();
        #pragma unroll
        for (int kk = 0; kk < 32; ++kk) {
            float a[8];
            #pragma unroll
            for (int m = 0; m < 8; ++m) a[m] = As[ty + 16 * m][kk];
            const float4 b0 = *(const float4*)&Bs[kk][tx * 8];
            const float4 b1 = *(const float4*)&Bs[kk][tx * 8 + 4];
            const float bcol[8] = {b0.x, b0.y, b0.z, b0.w, b1.x, b1.y, b1.z, b1.w};
            #pragma unroll
            for (int m = 0; m < 8; ++m)
                #pragma unroll
                for (int c = 0; c < 8; ++c)
                    acc[m][c] = fmaf(a[m], bcol[c], acc[m][c]);
        }
    }

    // fused LayerNorm (+ReLU) over the 128 cols of each row (16 lanes share a row)
    #pragma unroll
    for (int m = 0; m < 8; ++m) {
        float s = 0.f, sq = 0.f;
        #pragma unroll
        for (int c = 0; c < 8; ++c) { s += acc[m][c]; sq += acc[m][c] * acc[m][c]; }
        #pragma unroll
        for (int o = 1; o < 16; o <<= 1) {
            s += __shfl_xor(s, o, 64);
            sq += __shfl_xor(sq, o, 64);
        }
        const float mean = s * (1.f / 128.f);
        const float var = sq * (1.f / 128.f) - mean * mean;
        const float rs = rsqrtf(var + LEPS);
        const int rgm = row0 + ty + 16 * m;
        if (rgm < nrows) {
            #pragma unroll
            for (int q = 0; q < 4; ++q) {
                const float va = fmaxf((acc[m][2 * q]     - mean) * rs * gv[2 * q]     + bbv[2 * q],     0.f);
                const float vb = fmaxf((acc[m][2 * q + 1] - mean) * rs * gv[2 * q + 1] + bbv[2 * q + 1], 0.f);
                out[(size_t)rgm * 64 + tx * 4 + q] = pack2(va, vb);
            }
        }
    }
}

// ---------------- classifier: out = relu(LN(h@W1+b1)) @ W2 + b2 ----------------
__global__ __launch_bounds__(256) void k_cls(const uint* __restrict__ h32,
                                             const float* __restrict__ W1,   // 128x64
                                             const float* __restrict__ b1,
                                             const float* __restrict__ lg,
                                             const float* __restrict__ lb,
                                             const float* __restrict__ W2,   // 64
                                             const float* __restrict__ b2,
                                             float* __restrict__ outp) {
    __shared__ float W1s[128 * 64];
    __shared__ float W2s[64], b1s[64], lgs[64], lbs[64];
    __shared__ float hs[4][128];
    const int tid = threadIdx.x;
    for (int i = tid; i < 128 * 64; i += 256) W1s[i] = W1[i];
    if (tid < 64) { W2s[tid] = W2[tid]; b1s[tid] = b1[tid]; lgs[tid] = lg[tid]; lbs[tid] = lb[tid]; }
    const float b2v = b2[0];
    const int w = tid >> 6, lane = tid & 63;
    const int nb = gridDim.x;
    const int iters = (N_NODES + nb * 4 - 1) / (nb * 4);
    for (int it = 0; it < iters; ++it) {
        const int n = (it * nb + blockIdx.x) * 4 + w;
        const bool ok = n < N_NODES;
        __syncthreads();
        if (ok) {
            const uint hv = h32[(size_t)n * 64 + lane];
            hs[w][2 * lane]     = bf2f(hv & 0xFFFFu);
            hs[w][2 * lane + 1] = bf2f(hv >> 16);
        }
        __syncthreads();
        if (ok) {
            float acc = b1s[lane];
            #pragma unroll 4
            for (int k = 0; k < 128; ++k) acc = fmaf(hs[w][k], W1s[k * 64 + lane], acc);
            float s = acc, sq = acc * acc;
            #pragma unroll
            for (int o = 1; o < 64; o <<= 1) { s += __shfl_xor(s, o, 64); sq += __shfl_xor(sq, o, 64); }
            const float mean = s * (1.f / 64.f);
            const float var = sq * (1.f / 64.f) - mean * mean;
            const float z = fmaxf((acc - mean) * rsqrtf(var + LEPS) * lgs[lane] + lbs[lane], 0.f);
            float contrib = z * W2s[lane];
            #pragma unroll
            for (int o = 1; o < 64; o <<= 1) contrib += __shfl_xor(contrib, o, 64);
            if (lane == 0) outp[n] = contrib + b2v;
        }
    }
}

extern "C" void kernel_launch(void* const* d_in, const int* in_sizes, int n_in,
                              void* d_out, int out_size, void* d_ws, size_t ws_size,
                              hipStream_t stream) {
    const float* x      = (const float*)d_in[0];
    const int*   eidx   = (const int*)d_in[1];
    const int*   etype  = (const int*)d_in[2];
    const float* emb_W  = (const float*)d_in[3];
    const float* emb_b  = (const float*)d_in[4];
    const float* rel_W  = (const float*)d_in[5];
    const float* root_W = (const float*)d_in[6];
    const float* conv_b = (const float*)d_in[7];
    const float* ln_g   = (const float*)d_in[8];
    const float* ln_b   = (const float*)d_in[9];
    const float* cls_W1 = (const float*)d_in[10];
    const float* cls_b1 = (const float*)d_in[11];
    const float* cls_lg = (const float*)d_in[12];
    const float* cls_lb = (const float*)d_in[13];
    const float* cls_W2 = (const float*)d_in[14];
    const float* cls_b2 = (const float*)d_in[15];

    const int* srcv = eidx;
    const int* dstv = eidx + N_EDGES;

    // workspace layout (~141 MB total)
    char* ws = (char*)d_ws;
    size_t off = 0;
    auto alloc = [&](size_t bytes) { void* p = ws + off; off += (bytes + 255) & ~(size_t)255; return p; };
    uint* h0   = (uint*)alloc((size_t)N_NODES * 64 * 4);    // bf16 h, dword-packed
    uint* h1   = (uint*)alloc((size_t)N_NODES * 64 * 4);
    uint* M    = (uint*)alloc((size_t)N_NODES * 448 * 4);   // bf16 means, dword-packed
    int*  deg  = (int*)alloc((size_t)N_NODES * 4);
    int*  rp   = (int*)alloc((size_t)(N_NODES + 1) * 4);
    int*  fill = (int*)alloc((size_t)N_NODES * 4);
    int*  csr  = (int*)alloc((size_t)N_EDGES * 4);
    int*  bs   = (int*)alloc(1024);
    (void)ws_size; (void)n_in; (void)in_sizes; (void)out_size;

    const int SCAN_BLKS = (N_NODES + 255) / 256;   // 235

    k_embed<<<512, 256, 0, stream>>>(x, emb_W, emb_b, (ushort*)h0);
    k_zero2<<<SCAN_BLKS, 256, 0, stream>>>(deg, fill);
    k_deg<<<1024, 256, 0, stream>>>(dstv, deg);
    k_scan1<<<SCAN_BLKS, 256, 0, stream>>>(deg, rp, bs);
    k_scan2<<<1, 256, 0, stream>>>(bs, SCAN_BLKS);
    k_scanadd<<<SCAN_BLKS, 256, 0, stream>>>(rp, bs);
    k_scatter<<<1024, 256, 0, stream>>>(srcv, dstv, etype, rp, fill, csr);

    for (int l = 0; l < 2; ++l) {
        const uint* hin = l ? h1 : h0;
        uint* hout = l ? h0 : h1;
        k_agg<<<2048, 256, 0, stream>>>(hin, rp, csr, M);
        k_gemm_ln<<<(N_NODES + 127) / 128, 256, 0, stream>>>(
            M, hin,
            rel_W + (size_t)l * 896 * 128,
            root_W + (size_t)l * 128 * 128,
            conv_b + l * 128, ln_g + l * 128, ln_b + l * 128,
            hout, N_NODES);
    }
    k_cls<<<512, 256, 0, stream>>>(h0, cls_W1, cls_b1, cls_lg, cls_lb, cls_W2, cls_b2,
                                   (float*)d_out);
}

// Round 2
// 531.037 us; speedup vs baseline: 1.5562x; 1.5562x over previous
//
#include <hip/hip_runtime.h>
#include <hip/hip_bf16.h>

typedef unsigned int uint;
typedef unsigned short ushort;

#define N_NODES 60000
#define N_EDGES 600000
#define NREL 7
#define D_IN 64
#define DHID 128
#define D2 64
#define LEPS 1e-5f

typedef __attribute__((ext_vector_type(8))) short bf16x8v;   // 8 bf16 = 4 VGPRs
typedef __attribute__((ext_vector_type(4))) float f32x4v;    // MFMA accumulator

__device__ __forceinline__ float bf2f(uint u16) {
    return __uint_as_float(u16 << 16);
}
__device__ __forceinline__ uint f2bf(float f) {
    uint u = __float_as_uint(f);
    uint lsb = (u >> 16) & 1u;
    u += 0x7fffu + lsb;
    return u >> 16;
}
__device__ __forceinline__ uint pack2(float a, float b) {
    return f2bf(a) | (f2bf(b) << 16);
}

// ---------------- embedding: h0 = clip(x,-10,10) @ emb_W + emb_b (bf16 out) ----
__global__ __launch_bounds__(256) void k_embed(const float* __restrict__ x,
                                               const float* __restrict__ W,
                                               const float* __restrict__ bias,
                                               ushort* __restrict__ h) {
    __shared__ float Ws[D_IN * DHID];   // 32 KB
    __shared__ float xs[2][D_IN];
    __shared__ float brow[DHID];
    for (int i = threadIdx.x; i < D_IN * DHID; i += 256) Ws[i] = W[i];
    for (int i = threadIdx.x; i < DHID; i += 256) brow[i] = bias[i];
    const int g = threadIdx.x >> 7;      // node slot 0/1 in block
    const int c = threadIdx.x & 127;     // output column
    const int nb = gridDim.x;
    const int iters = (N_NODES + nb * 2 - 1) / (nb * 2);
    for (int it = 0; it < iters; ++it) {
        const int n = (it * nb + blockIdx.x) * 2 + g;
        __syncthreads();
        if (n < N_NODES && c < D_IN) {
            float v = x[(size_t)n * D_IN + c];
            xs[g][c] = fminf(fmaxf(v, -10.f), 10.f);
        }
        __syncthreads();
        if (n < N_NODES) {
            float acc = brow[c];
            #pragma unroll
            for (int k = 0; k < D_IN; ++k) acc = fmaf(xs[g][k], Ws[k * DHID + c], acc);
            h[(size_t)n * DHID + c] = (ushort)f2bf(acc);
        }
    }
}

// ---------------- B transpose + f32->bf16: Bt[l][j 0..127][k 0..1023] ----------
// k<896: rel_W[l][k/128][k%128][j]; k>=896: root_W[l][k-896][j]
__global__ __launch_bounds__(256) void k_bt(const float* __restrict__ relW,
                                            const float* __restrict__ rootW,
                                            ushort* __restrict__ Bt) {
    const int l  = blockIdx.x >> 5;
    const int kt = (blockIdx.x >> 1) & 15;   // 64-k tile
    const int jt = blockIdx.x & 1;           // 64-j tile
    __shared__ float t[64][65];
    const int tid = threadIdx.x;
    #pragma unroll
    for (int i = 0; i < 4; ++i) {
        const int idx = i * 256 + tid;       // 0..1023
        const int kr = idx >> 4;             // 0..63
        const int j4 = idx & 15;             // float4 index
        const int kg = kt * 64 + kr;
        const float* src = (kg < 896)
            ? (relW + (size_t)l * 896 * 128 + (size_t)kg * 128)
            : (rootW + (size_t)l * 128 * 128 + (size_t)(kg - 896) * 128);
        const float4 v = *(const float4*)(src + jt * 64 + j4 * 4);
        t[kr][j4 * 4 + 0] = v.x; t[kr][j4 * 4 + 1] = v.y;
        t[kr][j4 * 4 + 2] = v.z; t[kr][j4 * 4 + 3] = v.w;
    }
    __syncthreads();
    uint* btd = (uint*)Bt;
    #pragma unroll
    for (int i = 0; i < 8; ++i) {
        const int idx = i * 256 + tid;       // 0..2047
        const int jr = idx >> 5;             // 0..63
        const int kd = idx & 31;             // dword within 64-k tile
        const uint w = pack2(t[kd * 2][jr], t[kd * 2 + 1][jr]);
        btd[(size_t)l * 65536 + (size_t)(jt * 64 + jr) * 512 + kt * 32 + kd] = w;
    }
}

// ---------------- CSR build ----------------
__global__ void k_zero2(int* __restrict__ a, int* __restrict__ b) {
    int i = blockIdx.x * 256 + threadIdx.x;
    if (i < N_NODES) { a[i] = 0; b[i] = 0; }
}
__global__ void k_deg(const int* __restrict__ dst, int* __restrict__ deg) {
    for (int e = blockIdx.x * 256 + threadIdx.x; e < N_EDGES; e += gridDim.x * 256)
        atomicAdd(&deg[dst[e]], 1);
}
__global__ void k_scan1(const int* __restrict__ deg, int* __restrict__ rp, int* __restrict__ bs) {
    __shared__ int s[256];
    const int t = threadIdx.x;
    const int i = blockIdx.x * 256 + t;
    const int v = (i < N_NODES) ? deg[i] : 0;
    s[t] = v;
    __syncthreads();
    for (int o = 1; o < 256; o <<= 1) {
        int u = (t >= o) ? s[t - o] : 0;
        __syncthreads();
        s[t] += u;
        __syncthreads();
    }
    if (i < N_NODES) rp[i] = s[t] - v;
    if (t == 255) bs[blockIdx.x] = s[255];
}
__global__ void k_scan2(int* __restrict__ bs, int nb) {
    __shared__ int s[256];
    const int t = threadIdx.x;
    const int v = (t < nb) ? bs[t] : 0;
    s[t] = v;
    __syncthreads();
    for (int o = 1; o < 256; o <<= 1) {
        int u = (t >= o) ? s[t - o] : 0;
        __syncthreads();
        s[t] += u;
        __syncthreads();
    }
    if (t < nb) bs[t] = s[t] - v;
}
__global__ void k_scanadd(int* __restrict__ rp, const int* __restrict__ bs) {
    const int i = blockIdx.x * 256 + threadIdx.x;
    if (i < N_NODES) rp[i] += bs[blockIdx.x];
    if (blockIdx.x == 0 && threadIdx.x == 0) rp[N_NODES] = N_EDGES;
}
__global__ void k_scatter(const int* __restrict__ src, const int* __restrict__ dst,
                          const int* __restrict__ et, const int* __restrict__ rp,
                          int* __restrict__ fill, int* __restrict__ csr) {
    for (int e = blockIdx.x * 256 + threadIdx.x; e < N_EDGES; e += gridDim.x * 256) {
        const int d = dst[e];
        const int p = rp[d] + atomicAdd(&fill[d], 1);
        csr[p] = src[e] | (et[e] << 16);   // src < 65536, type < 8
    }
}

// ---------------- aggregation: M[n][r*128+d] = mean over type-r in-edges -------
__global__ __launch_bounds__(256) void k_agg(const uint* __restrict__ h32,
                                             const int* __restrict__ rp,
                                             const int* __restrict__ csr,
                                             uint* __restrict__ M32) {
    const int wave = (blockIdx.x * 256 + threadIdx.x) >> 6;
    const int lane = threadIdx.x & 63;
    const int nwaves = gridDim.x * 4;
    for (int n = wave; n < N_NODES; n += nwaves) {
        float a0[NREL], a1[NREL], cf[NREL];
        #pragma unroll
        for (int r = 0; r < NREL; ++r) { a0[r] = 0.f; a1[r] = 0.f; cf[r] = 0.f; }
        const int beg = rp[n], end = rp[n + 1];
        for (int e = beg; e < end; ++e) {
            const int ent = __builtin_amdgcn_readfirstlane(csr[e]);
            const int s = ent & 0xFFFF;
            const int r = ent >> 16;
            const uint hv = h32[(size_t)s * 64 + lane];
            const float v0 = bf2f(hv & 0xFFFFu);
            const float v1 = bf2f(hv >> 16);
            switch (r) {
                case 0: a0[0] += v0; a1[0] += v1; cf[0] += 1.f; break;
                case 1: a0[1] += v0; a1[1] += v1; cf[1] += 1.f; break;
                case 2: a0[2] += v0; a1[2] += v1; cf[2] += 1.f; break;
                case 3: a0[3] += v0; a1[3] += v1; cf[3] += 1.f; break;
                case 4: a0[4] += v0; a1[4] += v1; cf[4] += 1.f; break;
                case 5: a0[5] += v0; a1[5] += v1; cf[5] += 1.f; break;
                default: a0[6] += v0; a1[6] += v1; cf[6] += 1.f; break;
            }
        }
        const size_t base = (size_t)n * 448 + lane;
        #pragma unroll
        for (int r = 0; r < NREL; ++r) {
            const float sc = 1.f / fmaxf(cf[r], 1.f);
            M32[base + r * 64] = pack2(a0[r] * sc, a1[r] * sc);
        }
    }
}

// ---------------- MFMA GEMM + LayerNorm + ReLU ----------------
// C[n][j] = sum_k896 M[n][k]*B[k][j] + sum_k128 h[n][k]*Broot[k][j] + bias[j]
// A = [M | h] bf16, B pre-transposed bf16 Bt[j][k]. 128x128 tile, BK=64,
// 4 waves (2x2), each 64x64 via 4x4 frags of mfma_f32_16x16x32_bf16.
// LDS XOR-swizzle s = G ^ (row&7) on 16B granules (G4 fix).
__global__ __launch_bounds__(256) void k_gemm_mfma(const ushort* __restrict__ A1,  // [60000][896]
                                                   const ushort* __restrict__ A2,  // [60000][128]
                                                   const ushort* __restrict__ Bt,  // [128][1024]
                                                   const float* __restrict__ bias,
                                                   const float* __restrict__ g,
                                                   const float* __restrict__ bb,
                                                   uint* __restrict__ out,         // bf16 dwords, stride 64
                                                   int nrows) {
    __shared__ alignas(16) union {
        struct { ushort a[128 * 64]; ushort b[128 * 64]; } s;  // 32 KB staging
        float ep[64 * 132];                                    // 33 KB epilogue half
    } u;
    __shared__ float sbi[128], sg[128], sbb[128];

    const int tid = threadIdx.x;
    if (tid < 128) { sbi[tid] = bias[tid]; sg[tid] = g[tid]; sbb[tid] = bb[tid]; }
    const int lane = tid & 63;
    const int wid = tid >> 6;
    const int wrow = wid >> 1, wcol = wid & 1;
    const int row0 = blockIdx.x * 128;

    // staging address precompute: thread handles granules p = i*256+tid
    size_t aoffM[4], aoffH[4];
    const ushort* bptr[4];
    int dstoff[4];
    #pragma unroll
    for (int i = 0; i < 4; ++i) {
        const int p = i * 256 + tid;
        const int r = p >> 3, G = p & 7;
        const int rg = min(row0 + r, nrows - 1);
        aoffM[i] = (size_t)rg * 896 + G * 8;
        aoffH[i] = (size_t)rg * 128 + G * 8;
        bptr[i] = Bt + (size_t)r * 1024 + G * 8;
        dstoff[i] = (r * 8 + (G ^ (r & 7))) * 8;   // swizzled LDS granule
    }

    f32x4v acc[4][4];
    #pragma unroll
    for (int fm = 0; fm < 4; ++fm)
        #pragma unroll
        for (int fn = 0; fn < 4; ++fn)
            acc[fm][fn] = (f32x4v){0.f, 0.f, 0.f, 0.f};

    uint4 ra[4], rb[4];
    auto load_t = [&](int kt) {
        #pragma unroll
        for (int i = 0; i < 4; ++i) {
            const ushort* ap = (kt < 14) ? (A1 + aoffM[i] + kt * 64)
                                         : (A2 + aoffH[i] + (kt - 14) * 64);
            ra[i] = *(const uint4*)ap;
            rb[i] = *(const uint4*)(bptr[i] + kt * 64);
        }
    };
    load_t(0);

    #pragma unroll 1
    for (int kt = 0; kt < 16; ++kt) {
        __syncthreads();                       // previous compute done with LDS
        #pragma unroll
        for (int i = 0; i < 4; ++i) {
            *(uint4*)&u.s.a[dstoff[i]] = ra[i];
            *(uint4*)&u.s.b[dstoff[i]] = rb[i];
        }
        __syncthreads();
        if (kt < 15) load_t(kt + 1);           // prefetch overlaps compute
        #pragma unroll
        for (int kh = 0; kh < 2; ++kh) {
            bf16x8v af[4], bfr[4];
            #pragma unroll
            for (int f = 0; f < 4; ++f) {
                const int rowa = wrow * 64 + f * 16 + (lane & 15);
                const int sa = ((kh * 4) + (lane >> 4)) ^ (rowa & 7);
                af[f] = *(const bf16x8v*)&u.s.a[rowa * 64 + sa * 8];
                const int rowb = wcol * 64 + f * 16 + (lane & 15);
                const int sb = ((kh * 4) + (lane >> 4)) ^ (rowb & 7);
                bfr[f] = *(const bf16x8v*)&u.s.b[rowb * 64 + sb * 8];
            }
            #pragma unroll
            for (int fm = 0; fm < 4; ++fm)
                #pragma unroll
                for (int fn = 0; fn < 4; ++fn)
                    acc[fm][fn] = __builtin_amdgcn_mfma_f32_16x16x32_bf16(
                        af[fm], bfr[fn], acc[fm][fn], 0, 0, 0);
        }
    }

    // -------- fused LayerNorm + ReLU epilogue, two 64-row halves --------
    __syncthreads();
    #pragma unroll 1
    for (int hh = 0; hh < 2; ++hh) {
        if (wrow == hh) {
            #pragma unroll
            for (int fm = 0; fm < 4; ++fm) {
                const int rl = fm * 16 + (lane >> 4) * 4;
                #pragma unroll
                for (int fn = 0; fn < 4; ++fn) {
                    const int cl = wcol * 64 + fn * 16 + (lane & 15);
                    const float bi = sbi[cl];
                    #pragma unroll
                    for (int r = 0; r < 4; ++r)
                        u.ep[(rl + r) * 132 + cl] = acc[fm][fn][r] + bi;
                }
            }
        }
        __syncthreads();
        {
            const int r_loc = tid >> 2, cb = tid & 3;   // 4 threads per row
            const int row_g = row0 + hh * 64 + r_loc;
            float v[32];
            float s = 0.f, sq = 0.f;
            #pragma unroll
            for (int q = 0; q < 8; ++q) {
                const float4 t4 = *(const float4*)&u.ep[r_loc * 132 + cb * 32 + q * 4];
                v[4 * q + 0] = t4.x; v[4 * q + 1] = t4.y;
                v[4 * q + 2] = t4.z; v[4 * q + 3] = t4.w;
                s += t4.x + t4.y + t4.z + t4.w;
                sq += t4.x * t4.x + t4.y * t4.y + t4.z * t4.z + t4.w * t4.w;
            }
            s += __shfl_xor(s, 1, 64); sq += __shfl_xor(sq, 1, 64);
            s += __shfl_xor(s, 2, 64); sq += __shfl_xor(sq, 2, 64);
            const float mean = s * (1.f / 128.f);
            const float var = sq * (1.f / 128.f) - mean * mean;
            const float rs = rsqrtf(var + LEPS);
            if (row_g < nrows) {
                uint o[16];
                #pragma unroll
                for (int q2 = 0; q2 < 16; ++q2) {
                    const int c0 = cb * 32 + 2 * q2;
                    const float va = fmaxf((v[2 * q2] - mean) * rs * sg[c0] + sbb[c0], 0.f);
                    const float vb = fmaxf((v[2 * q2 + 1] - mean) * rs * sg[c0 + 1] + sbb[c0 + 1], 0.f);
                    o[q2] = pack2(va, vb);
                }
                uint* op = out + (size_t)row_g * 64 + cb * 16;
                *(uint4*)(op + 0)  = make_uint4(o[0], o[1], o[2], o[3]);
                *(uint4*)(op + 4)  = make_uint4(o[4], o[5], o[6], o[7]);
                *(uint4*)(op + 8)  = make_uint4(o[8], o[9], o[10], o[11]);
                *(uint4*)(op + 12) = make_uint4(o[12], o[13], o[14], o[15]);
            }
        }
        __syncthreads();
    }
}

// ---------------- classifier: out = relu(LN(h@W1+b1)) @ W2 + b2 ----------------
__global__ __launch_bounds__(256) void k_cls(const uint* __restrict__ h32,
                                             const float* __restrict__ W1,   // 128x64
                                             const float* __restrict__ b1,
                                             const float* __restrict__ lg,
                                             const float* __restrict__ lb,
                                             const float* __restrict__ W2,   // 64
                                             const float* __restrict__ b2,
                                             float* __restrict__ outp) {
    __shared__ float W1s[128 * 64];
    __shared__ float W2s[64], b1s[64], lgs[64], lbs[64];
    __shared__ float hs[4][128];
    const int tid = threadIdx.x;
    for (int i = tid; i < 128 * 64; i += 256) W1s[i] = W1[i];
    if (tid < 64) { W2s[tid] = W2[tid]; b1s[tid] = b1[tid]; lgs[tid] = lg[tid]; lbs[tid] = lb[tid]; }
    const float b2v = b2[0];
    const int w = tid >> 6, lane = tid & 63;
    const int nb = gridDim.x;
    const int iters = (N_NODES + nb * 4 - 1) / (nb * 4);
    for (int it = 0; it < iters; ++it) {
        const int n = (it * nb + blockIdx.x) * 4 + w;
        const bool ok = n < N_NODES;
        __syncthreads();
        if (ok) {
            const uint hv = h32[(size_t)n * 64 + lane];
            hs[w][2 * lane]     = bf2f(hv & 0xFFFFu);
            hs[w][2 * lane + 1] = bf2f(hv >> 16);
        }
        __syncthreads();
        if (ok) {
            float acc = b1s[lane];
            #pragma unroll 4
            for (int k = 0; k < 128; ++k) acc = fmaf(hs[w][k], W1s[k * 64 + lane], acc);
            float s = acc, sq = acc * acc;
            #pragma unroll
            for (int o = 1; o < 64; o <<= 1) { s += __shfl_xor(s, o, 64); sq += __shfl_xor(sq, o, 64); }
            const float mean = s * (1.f / 64.f);
            const float var = sq * (1.f / 64.f) - mean * mean;
            const float z = fmaxf((acc - mean) * rsqrtf(var + LEPS) * lgs[lane] + lbs[lane], 0.f);
            float contrib = z * W2s[lane];
            #pragma unroll
            for (int o = 1; o < 64; o <<= 1) contrib += __shfl_xor(contrib, o, 64);
            if (lane == 0) outp[n] = contrib + b2v;
        }
    }
}

extern "C" void kernel_launch(void* const* d_in, const int* in_sizes, int n_in,
                              void* d_out, int out_size, void* d_ws, size_t ws_size,
                              hipStream_t stream) {
    const float* x      = (const float*)d_in[0];
    const int*   eidx   = (const int*)d_in[1];
    const int*   etype  = (const int*)d_in[2];
    const float* emb_W  = (const float*)d_in[3];
    const float* emb_b  = (const float*)d_in[4];
    const float* rel_W  = (const float*)d_in[5];
    const float* root_W = (const float*)d_in[6];
    const float* conv_b = (const float*)d_in[7];
    const float* ln_g   = (const float*)d_in[8];
    const float* ln_b   = (const float*)d_in[9];
    const float* cls_W1 = (const float*)d_in[10];
    const float* cls_b1 = (const float*)d_in[11];
    const float* cls_lg = (const float*)d_in[12];
    const float* cls_lb = (const float*)d_in[13];
    const float* cls_W2 = (const float*)d_in[14];
    const float* cls_b2 = (const float*)d_in[15];

    const int* srcv = eidx;
    const int* dstv = eidx + N_EDGES;

    // workspace layout (~142 MB total)
    char* ws = (char*)d_ws;
    size_t off = 0;
    auto alloc = [&](size_t bytes) { void* p = ws + off; off += (bytes + 255) & ~(size_t)255; return p; };
    uint* h0   = (uint*)alloc((size_t)N_NODES * 64 * 4);    // bf16 h, dword-packed
    uint* h1   = (uint*)alloc((size_t)N_NODES * 64 * 4);
    uint* M    = (uint*)alloc((size_t)N_NODES * 448 * 4);   // bf16 means, dword-packed
    int*  deg  = (int*)alloc((size_t)N_NODES * 4);
    int*  rp   = (int*)alloc((size_t)(N_NODES + 1) * 4);
    int*  fill = (int*)alloc((size_t)N_NODES * 4);
    int*  csr  = (int*)alloc((size_t)N_EDGES * 4);
    int*  bs   = (int*)alloc(1024);
    ushort* Btb = (ushort*)alloc((size_t)2 * 128 * 1024 * 2);  // bf16 B^T per layer
    (void)ws_size; (void)n_in; (void)in_sizes; (void)out_size;

    const int SCAN_BLKS = (N_NODES + 255) / 256;   // 235
    const int GEMM_BLKS = (N_NODES + 127) / 128;   // 469

    k_bt<<<64, 256, 0, stream>>>(rel_W, root_W, Btb);
    k_embed<<<512, 256, 0, stream>>>(x, emb_W, emb_b, (ushort*)h0);
    k_zero2<<<SCAN_BLKS, 256, 0, stream>>>(deg, fill);
    k_deg<<<1024, 256, 0, stream>>>(dstv, deg);
    k_scan1<<<SCAN_BLKS, 256, 0, stream>>>(deg, rp, bs);
    k_scan2<<<1, 256, 0, stream>>>(bs, SCAN_BLKS);
    k_scanadd<<<SCAN_BLKS, 256, 0, stream>>>(rp, bs);
    k_scatter<<<1024, 256, 0, stream>>>(srcv, dstv, etype, rp, fill, csr);

    for (int l = 0; l < 2; ++l) {
        const uint* hin = l ? h1 : h0;
        uint* hout = l ? h0 : h1;
        k_agg<<<2048, 256, 0, stream>>>(hin, rp, csr, M);
        k_gemm_mfma<<<GEMM_BLKS, 256, 0, stream>>>(
            (const ushort*)M, (const ushort*)hin,
            Btb + (size_t)l * 131072,
            conv_b + l * 128, ln_g + l * 128, ln_b + l * 128,
            hout, N_NODES);
    }
    k_cls<<<512, 256, 0, stream>>>(h0, cls_W1, cls_b1, cls_lg, cls_lb, cls_W2, cls_b2,
                                   (float*)d_out);
}

// Round 3
// 351.603 us; speedup vs baseline: 2.3503x; 1.5103x over previous
//
#include <hip/hip_runtime.h>
#include <hip/hip_bf16.h>

typedef unsigned int uint;
typedef unsigned short ushort;

#define N_NODES 60000
#define N_EDGES 600000
#define NREL 7
#define NSEG (N_NODES * 8)    // (node, rel) segments, rel padded to 8
#define D_IN 64
#define DHID 128
#define LEPS 1e-5f

typedef __attribute__((ext_vector_type(8))) short bf16x8v;   // 8 bf16 = 4 VGPRs
typedef __attribute__((ext_vector_type(4))) float f32x4v;    // MFMA accumulator

#define AS1C(p) ((const __attribute__((address_space(1))) void*)(p))
#define AS3(p)  ((__attribute__((address_space(3))) void*)(p))

__device__ __forceinline__ float bf2f(uint u16) {
    return __uint_as_float(u16 << 16);
}
__device__ __forceinline__ uint f2bf(float f) {
    uint u = __float_as_uint(f);
    uint lsb = (u >> 16) & 1u;
    u += 0x7fffu + lsb;
    return u >> 16;
}
__device__ __forceinline__ uint pack2(float a, float b) {
    return f2bf(a) | (f2bf(b) << 16);
}

// ---------------- embedding: h0 = clip(x,-10,10) @ emb_W + emb_b (bf16 out) ----
__global__ __launch_bounds__(256) void k_embed(const float* __restrict__ x,
                                               const float* __restrict__ W,
                                               const float* __restrict__ bias,
                                               ushort* __restrict__ h) {
    __shared__ float Ws[D_IN * DHID];   // 32 KB
    __shared__ float xs[2][D_IN];
    __shared__ float brow[DHID];
    for (int i = threadIdx.x; i < D_IN * DHID; i += 256) Ws[i] = W[i];
    for (int i = threadIdx.x; i < DHID; i += 256) brow[i] = bias[i];
    const int g = threadIdx.x >> 7;      // node slot 0/1 in block
    const int c = threadIdx.x & 127;     // output column
    const int nb = gridDim.x;
    const int iters = (N_NODES + nb * 2 - 1) / (nb * 2);
    for (int it = 0; it < iters; ++it) {
        const int n = (it * nb + blockIdx.x) * 2 + g;
        __syncthreads();
        if (n < N_NODES && c < D_IN) {
            float v = x[(size_t)n * D_IN + c];
            xs[g][c] = fminf(fmaxf(v, -10.f), 10.f);
        }
        __syncthreads();
        if (n < N_NODES) {
            float acc = brow[c];
            #pragma unroll
            for (int k = 0; k < D_IN; ++k) acc = fmaf(xs[g][k], Ws[k * DHID + c], acc);
            h[(size_t)n * DHID + c] = (ushort)f2bf(acc);
        }
    }
}

// ---------------- B transpose + f32->bf16: Bt[l][j 0..127][k 0..1023] ----------
__global__ __launch_bounds__(256) void k_bt(const float* __restrict__ relW,
                                            const float* __restrict__ rootW,
                                            ushort* __restrict__ Bt) {
    const int l  = blockIdx.x >> 5;
    const int kt = (blockIdx.x >> 1) & 15;   // 64-k tile
    const int jt = blockIdx.x & 1;           // 64-j tile
    __shared__ float t[64][65];
    const int tid = threadIdx.x;
    #pragma unroll
    for (int i = 0; i < 4; ++i) {
        const int idx = i * 256 + tid;       // 0..1023
        const int kr = idx >> 4;             // 0..63
        const int j4 = idx & 15;             // float4 index
        const int kg = kt * 64 + kr;
        const float* src = (kg < 896)
            ? (relW + (size_t)l * 896 * 128 + (size_t)kg * 128)
            : (rootW + (size_t)l * 128 * 128 + (size_t)(kg - 896) * 128);
        const float4 v = *(const float4*)(src + jt * 64 + j4 * 4);
        t[kr][j4 * 4 + 0] = v.x; t[kr][j4 * 4 + 1] = v.y;
        t[kr][j4 * 4 + 2] = v.z; t[kr][j4 * 4 + 3] = v.w;
    }
    __syncthreads();
    uint* btd = (uint*)Bt;
    #pragma unroll
    for (int i = 0; i < 8; ++i) {
        const int idx = i * 256 + tid;       // 0..2047
        const int jr = idx >> 5;             // 0..63
        const int kd = idx & 31;             // dword within 64-k tile
        const uint w = pack2(t[kd * 2][jr], t[kd * 2 + 1][jr]);
        btd[(size_t)l * 65536 + (size_t)(jt * 64 + jr) * 512 + kt * 32 + kd] = w;
    }
}

// ---------------- CSR build over (dst, rel) segments ----------------
__global__ void k_zero(int* __restrict__ a, int n) {
    const int i = blockIdx.x * 256 + threadIdx.x;
    if (i < n) a[i] = 0;
}
__global__ void k_deg(const int* __restrict__ dst, const int* __restrict__ et,
                      int* __restrict__ deg8) {
    for (int e = blockIdx.x * 256 + threadIdx.x; e < N_EDGES; e += gridDim.x * 256)
        atomicAdd(&deg8[dst[e] * 8 + et[e]], 1);
}
__global__ void k_scan1(const int* __restrict__ in, int* __restrict__ out,
                        int* __restrict__ bsum, int n) {
    __shared__ int s[256];
    const int t = threadIdx.x;
    const int i = blockIdx.x * 256 + t;
    const int v = (i < n) ? in[i] : 0;
    s[t] = v;
    __syncthreads();
    for (int o = 1; o < 256; o <<= 1) {
        int u = (t >= o) ? s[t - o] : 0;
        __syncthreads();
        s[t] += u;
        __syncthreads();
    }
    if (i < n) out[i] = s[t] - v;   // exclusive within block
    if (t == 255) bsum[blockIdx.x] = s[255];
}
__global__ void k_scan2(int* __restrict__ bs, int nb) {
    __shared__ int s[256];
    const int t = threadIdx.x;
    const int v = (t < nb) ? bs[t] : 0;
    s[t] = v;
    __syncthreads();
    for (int o = 1; o < 256; o <<= 1) {
        int u = (t >= o) ? s[t - o] : 0;
        __syncthreads();
        s[t] += u;
        __syncthreads();
    }
    if (t < nb) bs[t] = s[t] - v;   // exclusive
}
__global__ void k_scanadd(int* __restrict__ a, const int* __restrict__ bsums,
                          int n, int setlast) {
    const int i = blockIdx.x * 256 + threadIdx.x;
    if (i < n) a[i] += bsums[blockIdx.x];
    if (setlast && blockIdx.x == 0 && threadIdx.x == 0) a[n] = N_EDGES;
}
__global__ void k_scatter(const int* __restrict__ src, const int* __restrict__ dst,
                          const int* __restrict__ et, const int* __restrict__ rp8,
                          int* __restrict__ fill8, ushort* __restrict__ csr16) {
    for (int e = blockIdx.x * 256 + threadIdx.x; e < N_EDGES; e += gridDim.x * 256) {
        const int key = dst[e] * 8 + et[e];
        const int p = rp8[key] + atomicAdd(&fill8[key], 1);
        csr16[p] = (ushort)src[e];    // src < 65536
    }
}

// ---------------- aggregation: wave per node, 7 (node,rel) sub-segments -------
__global__ __launch_bounds__(256) void k_agg(const uint* __restrict__ h32,
                                             const int* __restrict__ rp8,
                                             const ushort* __restrict__ csr16,
                                             uint* __restrict__ M32) {
    const int wave = (blockIdx.x * 256 + threadIdx.x) >> 6;
    const int lane = threadIdx.x & 63;
    const int nwaves = gridDim.x * 4;
    for (int n = wave; n < N_NODES; n += nwaves) {
        int beg = rp8[n * 8];
        #pragma unroll 1
        for (int r = 0; r < NREL; ++r) {
            const int end = rp8[n * 8 + r + 1];
            float a0 = 0.f, a1 = 0.f;
            for (int e = beg; e < end; ++e) {
                const int s = __builtin_amdgcn_readfirstlane((int)csr16[e]);
                const uint hv = h32[(size_t)s * 64 + lane];
                a0 += bf2f(hv & 0xFFFFu);
                a1 += bf2f(hv >> 16);
            }
            const float rsc = 1.f / (float)max(end - beg, 1);
            M32[(size_t)n * 448 + r * 64 + lane] = pack2(a0 * rsc, a1 * rsc);
            beg = end;
        }
    }
}

// ---------------- MFMA GEMM + LayerNorm + ReLU (8 waves, gload_lds pipeline) ----
// C[n][j] = sum_k1024 [M|h][n][k] * Bt[j][k] + bias[j]; LN over j; ReLU; bf16.
// 128x128 tile, BK=64, double-buffered LDS staged via global_load_lds width=16
// with pre-swizzled GLOBAL source (rule #21); counted vmcnt(4) + raw s_barrier.
__global__ __launch_bounds__(512) void k_gemm_mfma(const ushort* __restrict__ A1,  // [N][896]
                                                   const ushort* __restrict__ A2,  // [N][128]
                                                   const ushort* __restrict__ Bt,  // [128][1024]
                                                   const float* __restrict__ bias,
                                                   const float* __restrict__ g,
                                                   const float* __restrict__ bb,
                                                   uint* __restrict__ out,         // bf16 dwords
                                                   int nrows) {
    __shared__ alignas(16) union {
        struct { ushort a[2][8192]; ushort b[2][8192]; } s;   // 64 KB staging (dbuf)
        float ep[64 * 132];                                   // 33 KB epilogue half
    } u;
    __shared__ float sbi[DHID], sg[DHID], sbb[DHID];

    const int tid = threadIdx.x;
    if (tid < DHID) { sbi[tid] = bias[tid]; sg[tid] = g[tid]; sbb[tid] = bb[tid]; }
    const int lane = tid & 63;
    const int wid = tid >> 6;        // 0..7
    const int wrow = wid >> 1;       // 0..3: 32-row band
    const int wcol = wid & 1;        // 0..1: 64-col band
    const int row0 = blockIdx.x * 128;

    // staging descriptors: thread covers LDS granules p = hf*512 + wid*64 + lane.
    // LDS is LINEAR (gload_lds: uniform base + lane*16); the SOURCE granule is
    // inverse-swizzled: slot s=p&7 of row r holds global granule G = s ^ (r&7).
    int prow[2], pG[2], arow[2];
    #pragma unroll
    for (int hf = 0; hf < 2; ++hf) {
        const int p = hf * 512 + wid * 64 + lane;
        const int r = p >> 3;
        prow[hf] = r;
        pG[hf] = (p & 7) ^ (r & 7);
        arow[hf] = min(row0 + r, nrows - 1);
    }

    auto stage = [&](int buf, int kt) {
        #pragma unroll
        for (int hf = 0; hf < 2; ++hf) {
            const ushort* ga = (kt < 14)
                ? (A1 + (size_t)arow[hf] * 896 + kt * 64 + pG[hf] * 8)
                : (A2 + (size_t)arow[hf] * 128 + (kt - 14) * 64 + pG[hf] * 8);
            __builtin_amdgcn_global_load_lds(AS1C(ga),
                AS3(&u.s.a[buf][(hf * 512 + wid * 64) * 8]), 16, 0, 0);
            const ushort* gb = Bt + (size_t)prow[hf] * 1024 + kt * 64 + pG[hf] * 8;
            __builtin_amdgcn_global_load_lds(AS1C(gb),
                AS3(&u.s.b[buf][(hf * 512 + wid * 64) * 8]), 16, 0, 0);
        }
    };

    f32x4v acc[2][4];
    #pragma unroll
    for (int fm = 0; fm < 2; ++fm)
        #pragma unroll
        for (int fn = 0; fn < 4; ++fn)
            acc[fm][fn] = (f32x4v){0.f, 0.f, 0.f, 0.f};

    auto compute = [&](int buf) {
        #pragma unroll
        for (int kh = 0; kh < 2; ++kh) {
            bf16x8v af[2], bfr[4];
            #pragma unroll
            for (int fm = 0; fm < 2; ++fm) {
                const int rowa = wrow * 32 + fm * 16 + (lane & 15);
                const int sa = (kh * 4 + (lane >> 4)) ^ (rowa & 7);
                af[fm] = *(const bf16x8v*)&u.s.a[buf][rowa * 64 + sa * 8];
            }
            #pragma unroll
            for (int fn = 0; fn < 4; ++fn) {
                const int rowb = wcol * 64 + fn * 16 + (lane & 15);
                const int sb = (kh * 4 + (lane >> 4)) ^ (rowb & 7);
                bfr[fn] = *(const bf16x8v*)&u.s.b[buf][rowb * 64 + sb * 8];
            }
            #pragma unroll
            for (int fm = 0; fm < 2; ++fm)
                #pragma unroll
                for (int fn = 0; fn < 4; ++fn)
                    acc[fm][fn] = __builtin_amdgcn_mfma_f32_16x16x32_bf16(
                        af[fm], bfr[fn], acc[fm][fn], 0, 0, 0);
        }
    };

    stage(0, 0);                       // outstanding: 4
    #pragma unroll 1
    for (int kt = 0; kt < 16; ++kt) {
        const int cur = kt & 1;
        if (kt < 15) {
            stage(cur ^ 1, kt + 1);    // outstanding: 8 (4 cur + 4 next)
            asm volatile("s_waitcnt vmcnt(4)\n\ts_barrier" ::: "memory");  // cur done
        } else {
            asm volatile("s_waitcnt vmcnt(0)\n\ts_barrier" ::: "memory");
        }
        compute(cur);
        asm volatile("s_barrier" ::: "memory");  // protect cur before next overwrite
    }
    __syncthreads();

    // -------- fused LayerNorm + ReLU epilogue, two 64-row halves --------
    const int hw = wrow >> 1;
    #pragma unroll 1
    for (int hh = 0; hh < 2; ++hh) {
        if (hw == hh) {
            #pragma unroll
            for (int fm = 0; fm < 2; ++fm) {
                const int rl = (wrow & 1) * 32 + fm * 16 + (lane >> 4) * 4;
                #pragma unroll
                for (int fn = 0; fn < 4; ++fn) {
                    const int cl = wcol * 64 + fn * 16 + (lane & 15);
                    const float bi = sbi[cl];
                    #pragma unroll
                    for (int r = 0; r < 4; ++r)
                        u.ep[(rl + r) * 132 + cl] = acc[fm][fn][r] + bi;
                }
            }
        }
        __syncthreads();
        {
            const int r_loc = tid >> 3, cb = tid & 7;   // 8 threads per row
            const int row_g = row0 + hh * 64 + r_loc;
            float v[16];
            float s = 0.f, sq = 0.f;
            #pragma unroll
            for (int q = 0; q < 4; ++q) {
                const float4 t4 = *(const float4*)&u.ep[r_loc * 132 + cb * 16 + q * 4];
                v[4 * q + 0] = t4.x; v[4 * q + 1] = t4.y;
                v[4 * q + 2] = t4.z; v[4 * q + 3] = t4.w;
                s += t4.x + t4.y + t4.z + t4.w;
                sq += t4.x * t4.x + t4.y * t4.y + t4.z * t4.z + t4.w * t4.w;
            }
            s += __shfl_xor(s, 1, 64); sq += __shfl_xor(sq, 1, 64);
            s += __shfl_xor(s, 2, 64); sq += __shfl_xor(sq, 2, 64);
            s += __shfl_xor(s, 4, 64); sq += __shfl_xor(sq, 4, 64);
            const float mean = s * (1.f / 128.f);
            const float var = sq * (1.f / 128.f) - mean * mean;
            const float rs = rsqrtf(var + LEPS);
            if (row_g < nrows) {
                uint o[8];
                #pragma unroll
                for (int q2 = 0; q2 < 8; ++q2) {
                    const int c0 = cb * 16 + 2 * q2;
                    const float va = fmaxf((v[2 * q2]     - mean) * rs * sg[c0]     + sbb[c0],     0.f);
                    const float vb = fmaxf((v[2 * q2 + 1] - mean) * rs * sg[c0 + 1] + sbb[c0 + 1], 0.f);
                    o[q2] = pack2(va, vb);
                }
                uint* op = out + (size_t)row_g * 64 + cb * 8;
                *(uint4*)(op + 0) = make_uint4(o[0], o[1], o[2], o[3]);
                *(uint4*)(op + 4) = make_uint4(o[4], o[5], o[6], o[7]);
            }
        }
        __syncthreads();
    }
}

// ---------------- classifier: MFMA h@W1 + in-register LN/ReLU/W2-dot ----------
__global__ __launch_bounds__(256) void k_cls(const ushort* __restrict__ h16,
                                             const float* __restrict__ W1,   // [128][64]
                                             const float* __restrict__ b1,
                                             const float* __restrict__ lg,
                                             const float* __restrict__ lb,
                                             const float* __restrict__ W2,   // [64]
                                             const float* __restrict__ b2,
                                             float* __restrict__ outp, int nrows) {
    __shared__ ushort Bs[16 * 64 * 8];   // [k-granule g][col j'][8 bf16], 16 KB
    const int tid = threadIdx.x;
    #pragma unroll
    for (int i = 0; i < 8; ++i) {
        const int q = i * 256 + tid;     // 2048 float4 = 8192 f32
        const int k = q >> 4;            // 0..127
        const int j0 = (q & 15) * 4;
        const float4 w = *(const float4*)(W1 + (size_t)k * 64 + j0);
        const int gg = k >> 3, kp = k & 7;
        const int jx = (gg & 3) << 4;
        Bs[(gg * 64 + ((j0 + 0) ^ jx)) * 8 + kp] = (ushort)f2bf(w.x);
        Bs[(gg * 64 + ((j0 + 1) ^ jx)) * 8 + kp] = (ushort)f2bf(w.y);
        Bs[(gg * 64 + ((j0 + 2) ^ jx)) * 8 + kp] = (ushort)f2bf(w.z);
        Bs[(gg * 64 + ((j0 + 3) ^ jx)) * 8 + kp] = (ushort)f2bf(w.w);
    }
    const int lane = tid & 63, wid = tid >> 6;
    const int l15 = lane & 15, lh = lane >> 4;
    float lgv[4], lbv[4], w2v[4], b1v[4];
    #pragma unroll
    for (int fn = 0; fn < 4; ++fn) {
        const int col = fn * 16 + l15;
        lgv[fn] = lg[col]; lbv[fn] = lb[col]; w2v[fn] = W2[col]; b1v[fn] = b1[col];
    }
    const float b2v = b2[0];
    __syncthreads();

    const int row0 = blockIdx.x * 128;
    f32x4v acc[2][4];
    #pragma unroll
    for (int fm = 0; fm < 2; ++fm)
        #pragma unroll
        for (int fn = 0; fn < 4; ++fn)
            acc[fm][fn] = (f32x4v){0.f, 0.f, 0.f, 0.f};

    #pragma unroll
    for (int kk = 0; kk < 4; ++kk) {
        bf16x8v af[2], bfr[4];
        #pragma unroll
        for (int fm = 0; fm < 2; ++fm) {
            const int row = min(row0 + wid * 32 + fm * 16 + l15, nrows - 1);
            af[fm] = *(const bf16x8v*)(h16 + (size_t)row * 128 + kk * 32 + lh * 8);
        }
        #pragma unroll
        for (int fn = 0; fn < 4; ++fn) {
            const int gg = kk * 4 + lh;
            const int jc = fn * 16 + l15;
            bfr[fn] = *(const bf16x8v*)&Bs[(gg * 64 + (jc ^ ((gg & 3) << 4))) * 8];
        }
        #pragma unroll
        for (int fm = 0; fm < 2; ++fm)
            #pragma unroll
            for (int fn = 0; fn < 4; ++fn)
                acc[fm][fn] = __builtin_amdgcn_mfma_f32_16x16x32_bf16(
                    af[fm], bfr[fn], acc[fm][fn], 0, 0, 0);
    }

    #pragma unroll
    for (int fm = 0; fm < 2; ++fm)
        #pragma unroll
        for (int r = 0; r < 4; ++r) {
            float c[4];
            float s = 0.f, sq = 0.f;
            #pragma unroll
            for (int fn = 0; fn < 4; ++fn) {
                c[fn] = acc[fm][fn][r] + b1v[fn];
                s += c[fn]; sq += c[fn] * c[fn];
            }
            s += __shfl_xor(s, 1, 64); sq += __shfl_xor(sq, 1, 64);
            s += __shfl_xor(s, 2, 64); sq += __shfl_xor(sq, 2, 64);
            s += __shfl_xor(s, 4, 64); sq += __shfl_xor(sq, 4, 64);
            s += __shfl_xor(s, 8, 64); sq += __shfl_xor(sq, 8, 64);
            const float mean = s * (1.f / 64.f);
            const float var = sq * (1.f / 64.f) - mean * mean;
            const float rs = rsqrtf(var + LEPS);
            float dot = 0.f;
            #pragma unroll
            for (int fn = 0; fn < 4; ++fn)
                dot += fmaxf((c[fn] - mean) * rs * lgv[fn] + lbv[fn], 0.f) * w2v[fn];
            dot += __shfl_xor(dot, 1, 64);
            dot += __shfl_xor(dot, 2, 64);
            dot += __shfl_xor(dot, 4, 64);
            dot += __shfl_xor(dot, 8, 64);
            const int row = row0 + wid * 32 + fm * 16 + lh * 4 + r;
            if (l15 == 0 && row < nrows) outp[row] = dot + b2v;
        }
}

extern "C" void kernel_launch(void* const* d_in, const int* in_sizes, int n_in,
                              void* d_out, int out_size, void* d_ws, size_t ws_size,
                              hipStream_t stream) {
    const float* x      = (const float*)d_in[0];
    const int*   eidx   = (const int*)d_in[1];
    const int*   etype  = (const int*)d_in[2];
    const float* emb_W  = (const float*)d_in[3];
    const float* emb_b  = (const float*)d_in[4];
    const float* rel_W  = (const float*)d_in[5];
    const float* root_W = (const float*)d_in[6];
    const float* conv_b = (const float*)d_in[7];
    const float* ln_g   = (const float*)d_in[8];
    const float* ln_b   = (const float*)d_in[9];
    const float* cls_W1 = (const float*)d_in[10];
    const float* cls_b1 = (const float*)d_in[11];
    const float* cls_lg = (const float*)d_in[12];
    const float* cls_lb = (const float*)d_in[13];
    const float* cls_W2 = (const float*)d_in[14];
    const float* cls_b2 = (const float*)d_in[15];

    const int* srcv = eidx;
    const int* dstv = eidx + N_EDGES;

    // workspace layout (~142 MB; scan temporaries overlaid inside M)
    char* ws = (char*)d_ws;
    size_t off = 0;
    auto alloc = [&](size_t bytes) { void* p = ws + off; off += (bytes + 255) & ~(size_t)255; return p; };
    uint*   h0    = (uint*)alloc((size_t)N_NODES * 64 * 4);     // bf16 h, dword-packed
    uint*   h1    = (uint*)alloc((size_t)N_NODES * 64 * 4);
    uint*   M     = (uint*)alloc((size_t)N_NODES * 448 * 4);    // bf16 means, dword-packed
    int*    rp8   = (int*)alloc((size_t)(NSEG + 1) * 4);
    ushort* csr16 = (ushort*)alloc((size_t)N_EDGES * 2);
    ushort* Btb   = (ushort*)alloc((size_t)2 * 128 * 1024 * 2); // bf16 B^T per layer
    // overlay (dead once k_agg first writes M):
    int* deg8 = (int*)M;                      // NSEG ints, doubles as fill counters
    int* bs   = (int*)((char*)M + (((size_t)NSEG * 4 + 255) & ~(size_t)255));
    int* bsE  = bs + 2048;
    int* bs2  = bsE + 2048;
    (void)ws_size; (void)n_in; (void)in_sizes; (void)out_size;

    const int ZB = (NSEG + 255) / 256;        // 1875
    const int GEMM_BLKS = (N_NODES + 127) / 128;   // 469

    k_bt<<<64, 256, 0, stream>>>(rel_W, root_W, Btb);
    k_embed<<<512, 256, 0, stream>>>(x, emb_W, emb_b, (ushort*)h0);
    k_zero<<<ZB, 256, 0, stream>>>(deg8, NSEG);
    k_deg<<<1024, 256, 0, stream>>>(dstv, etype, deg8);
    k_scan1<<<ZB, 256, 0, stream>>>(deg8, rp8, bs, NSEG);
    k_scan1<<<8, 256, 0, stream>>>(bs, bsE, bs2, ZB);
    k_scan2<<<1, 256, 0, stream>>>(bs2, 8);
    k_scanadd<<<8, 256, 0, stream>>>(bsE, bs2, ZB, 0);
    k_scanadd<<<ZB, 256, 0, stream>>>(rp8, bsE, NSEG, 1);
    k_zero<<<ZB, 256, 0, stream>>>(deg8, NSEG);    // reuse as fill counters
    k_scatter<<<1024, 256, 0, stream>>>(srcv, dstv, etype, rp8, deg8, csr16);

    for (int l = 0; l < 2; ++l) {
        const uint* hin = l ? h1 : h0;
        uint* hout = l ? h0 : h1;
        k_agg<<<2048, 256, 0, stream>>>(hin, rp8, csr16, M);
        k_gemm_mfma<<<GEMM_BLKS, 512, 0, stream>>>(
            (const ushort*)M, (const ushort*)hin,
            Btb + (size_t)l * 131072,
            conv_b + l * 128, ln_g + l * 128, ln_b + l * 128,
            hout, N_NODES);
    }
    k_cls<<<469, 256, 0, stream>>>((const ushort*)h0, cls_W1, cls_b1, cls_lg, cls_lb,
                                   cls_W2, cls_b2, (float*)d_out, N_NODES);
}

// Round 4
// 351.233 us; speedup vs baseline: 2.3528x; 1.0011x over previous
//
#include <hip/hip_runtime.h>
#include <hip/hip_bf16.h>

typedef unsigned int uint;
typedef unsigned short ushort;

#define N_NODES 60000
#define N_EDGES 600000
#define NREL 7
#define NSEG (NREL * N_NODES)   // (rel, node) segments, relation-major
#define D_IN 64
#define DHID 128
#define LEPS 1e-5f

typedef __attribute__((ext_vector_type(8))) short bf16x8v;   // 8 bf16 = 4 VGPRs
typedef __attribute__((ext_vector_type(4))) float f32x4v;    // MFMA accumulator

#define AS1C(p) ((const __attribute__((address_space(1))) void*)(p))
#define AS3(p)  ((__attribute__((address_space(3))) void*)(p))

__device__ __forceinline__ float bf2f(uint u16) {
    return __uint_as_float(u16 << 16);
}
__device__ __forceinline__ uint f2bf(float f) {
    uint u = __float_as_uint(f);
    uint lsb = (u >> 16) & 1u;
    u += 0x7fffu + lsb;
    return u >> 16;
}
__device__ __forceinline__ uint pack2(float a, float b) {
    return f2bf(a) | (f2bf(b) << 16);
}

// ---------------- embedding: h0 = clip(x,-10,10) @ emb_W + emb_b (bf16 out) ----
__global__ __launch_bounds__(256) void k_embed(const float* __restrict__ x,
                                               const float* __restrict__ W,
                                               const float* __restrict__ bias,
                                               ushort* __restrict__ h) {
    __shared__ float Ws[D_IN * DHID];   // 32 KB
    __shared__ float xs[2][D_IN];
    __shared__ float brow[DHID];
    for (int i = threadIdx.x; i < D_IN * DHID; i += 256) Ws[i] = W[i];
    for (int i = threadIdx.x; i < DHID; i += 256) brow[i] = bias[i];
    const int g = threadIdx.x >> 7;      // node slot 0/1 in block
    const int c = threadIdx.x & 127;     // output column
    const int nb = gridDim.x;
    const int iters = (N_NODES + nb * 2 - 1) / (nb * 2);
    for (int it = 0; it < iters; ++it) {
        const int n = (it * nb + blockIdx.x) * 2 + g;
        __syncthreads();
        if (n < N_NODES && c < D_IN) {
            float v = x[(size_t)n * D_IN + c];
            xs[g][c] = fminf(fmaxf(v, -10.f), 10.f);
        }
        __syncthreads();
        if (n < N_NODES) {
            float acc = brow[c];
            #pragma unroll
            for (int k = 0; k < D_IN; ++k) acc = fmaf(xs[g][k], Ws[k * DHID + c], acc);
            h[(size_t)n * DHID + c] = (ushort)f2bf(acc);
        }
    }
}

// ---------------- B transpose + f32->bf16: Bt[l][j 0..127][k 0..1023] ----------
__global__ __launch_bounds__(256) void k_bt(const float* __restrict__ relW,
                                            const float* __restrict__ rootW,
                                            ushort* __restrict__ Bt) {
    const int l  = blockIdx.x >> 5;
    const int kt = (blockIdx.x >> 1) & 15;   // 64-k tile
    const int jt = blockIdx.x & 1;           // 64-j tile
    __shared__ float t[64][65];
    const int tid = threadIdx.x;
    #pragma unroll
    for (int i = 0; i < 4; ++i) {
        const int idx = i * 256 + tid;       // 0..1023
        const int kr = idx >> 4;             // 0..63
        const int j4 = idx & 15;             // float4 index
        const int kg = kt * 64 + kr;
        const float* src = (kg < 896)
            ? (relW + (size_t)l * 896 * 128 + (size_t)kg * 128)
            : (rootW + (size_t)l * 128 * 128 + (size_t)(kg - 896) * 128);
        const float4 v = *(const float4*)(src + jt * 64 + j4 * 4);
        t[kr][j4 * 4 + 0] = v.x; t[kr][j4 * 4 + 1] = v.y;
        t[kr][j4 * 4 + 2] = v.z; t[kr][j4 * 4 + 3] = v.w;
    }
    __syncthreads();
    uint* btd = (uint*)Bt;
    #pragma unroll
    for (int i = 0; i < 8; ++i) {
        const int idx = i * 256 + tid;       // 0..2047
        const int jr = idx >> 5;             // 0..63
        const int kd = idx & 31;             // dword within 64-k tile
        const uint w = pack2(t[kd * 2][jr], t[kd * 2 + 1][jr]);
        btd[(size_t)l * 65536 + (size_t)(jt * 64 + jr) * 512 + kt * 32 + kd] = w;
    }
}

// ---------------- CSR build over (rel, dst) segments, relation-major ----------
__global__ void k_zero(int* __restrict__ a, int n) {
    const int i = blockIdx.x * 256 + threadIdx.x;
    if (i < n) a[i] = 0;
}
__global__ void k_deg(const int* __restrict__ dst, const int* __restrict__ et,
                      int* __restrict__ deg) {
    for (int e = blockIdx.x * 256 + threadIdx.x; e < N_EDGES; e += gridDim.x * 256)
        atomicAdd(&deg[et[e] * N_NODES + dst[e]], 1);
}
__global__ void k_scan1(const int* __restrict__ in, int* __restrict__ out,
                        int* __restrict__ bsum, int n) {
    __shared__ int s[256];
    const int t = threadIdx.x;
    const int i = blockIdx.x * 256 + t;
    const int v = (i < n) ? in[i] : 0;
    s[t] = v;
    __syncthreads();
    for (int o = 1; o < 256; o <<= 1) {
        int u = (t >= o) ? s[t - o] : 0;
        __syncthreads();
        s[t] += u;
        __syncthreads();
    }
    if (i < n) out[i] = s[t] - v;   // exclusive within block
    if (t == 255) bsum[blockIdx.x] = s[255];
}
__global__ void k_scan2(int* __restrict__ bs, int nb) {
    __shared__ int s[256];
    const int t = threadIdx.x;
    const int v = (t < nb) ? bs[t] : 0;
    s[t] = v;
    __syncthreads();
    for (int o = 1; o < 256; o <<= 1) {
        int u = (t >= o) ? s[t - o] : 0;
        __syncthreads();
        s[t] += u;
        __syncthreads();
    }
    if (t < nb) bs[t] = s[t] - v;   // exclusive
}
__global__ void k_scanadd(int* __restrict__ a, const int* __restrict__ bsums,
                          int n, int setlast) {
    const int i = blockIdx.x * 256 + threadIdx.x;
    if (i < n) a[i] += bsums[blockIdx.x];
    if (setlast && blockIdx.x == 0 && threadIdx.x == 0) a[n] = N_EDGES;
}
__global__ void k_scatter(const int* __restrict__ src, const int* __restrict__ dst,
                          const int* __restrict__ et, const int* __restrict__ rp,
                          int* __restrict__ fill, ushort* __restrict__ csr16) {
    for (int e = blockIdx.x * 256 + threadIdx.x; e < N_EDGES; e += gridDim.x * 256) {
        const int key = et[e] * N_NODES + dst[e];
        const int p = rp[key] + atomicAdd(&fill[key], 1);
        csr16[p] = (ushort)src[e];    // src < 65536
    }
}

// ---------------- fused gather-mean + MFMA GEMM + LayerNorm + ReLU ------------
// Block = 64 nodes x 128 out-cols. Per k-tile (BK=64): thread (nl=tid>>2,
// c=tid&3) aggregates mean over its (node, rel=kt>>1) segment for cols
// [c*16, c*16+16) of half kt&1, in f32 regs; writes swizzled bf16 A-tile to
// LDS. Root k-tiles 14/15 read h directly. B double-buffered via
// global_load_lds w/ pre-swizzled source. 4 waves (2x2), 16x16x32 MFMA.
__global__ __launch_bounds__(256, 3) void k_fused(const uint* __restrict__ h32,  // [N][64] dwords
                                                  const int* __restrict__ rp,    // [NSEG+1]
                                                  const ushort* __restrict__ csr16,
                                                  const ushort* __restrict__ Bt, // [128][1024]
                                                  const float* __restrict__ bias,
                                                  const float* __restrict__ g,
                                                  const float* __restrict__ bb,
                                                  uint* __restrict__ out,        // bf16 dwords
                                                  int nrows) {
    __shared__ alignas(16) union {
        struct { ushort a[64 * 64]; ushort b[2][128 * 64]; } s;  // 8 + 32 KB
        float ep[64 * 132];                                      // 33 KB epilogue
    } u;
    __shared__ float sbi[DHID], sg[DHID], sbb[DHID];

    const int tid = threadIdx.x;
    if (tid < DHID) { sbi[tid] = bias[tid]; sg[tid] = g[tid]; sbb[tid] = bb[tid]; }
    const int lane = tid & 63;
    const int wid = tid >> 6;          // 0..3
    const int wrow = wid >> 1;         // 0..1: 32-row band
    const int wcol = wid & 1;          // 0..1: 64-col band
    const int l15 = lane & 15, lh = lane >> 4;
    const int row0 = blockIdx.x * 64;
    const int nl = tid >> 2;           // node-local 0..63
    const int c  = tid & 3;            // 16-col chunk 0..3
    const int n  = min(row0 + nl, nrows - 1);

    // ---- B staging: linear LDS dest, inverse-swizzled global source ----
    auto stageB = [&](int buf, int kt) {
        #pragma unroll
        for (int q = 0; q < 4; ++q) {
            const int p = q * 256 + tid;                 // granule 0..1023
            const int row = p >> 3;
            const int G = (p & 7) ^ (row & 7);
            const ushort* gb = Bt + (size_t)row * 1024 + kt * 64 + G * 8;
            __builtin_amdgcn_global_load_lds(AS1C(gb),
                AS3(&u.s.b[buf][(q * 256 + wid * 64) * 8]), 16, 0, 0);
        }
    };

    // ---- gather: mean over (rel, n) segment (or root read), 16 f32 regs ----
    float ac[16];
    float sc;
    auto accum = [&](int s, int doff) {
        const uint* hp = h32 + (size_t)s * 64 + doff;
        const uint4 q0 = *(const uint4*)hp;
        const uint4 q1 = *(const uint4*)(hp + 4);
        ac[0] += bf2f(q0.x & 0xFFFFu);  ac[1] += bf2f(q0.x >> 16);
        ac[2] += bf2f(q0.y & 0xFFFFu);  ac[3] += bf2f(q0.y >> 16);
        ac[4] += bf2f(q0.z & 0xFFFFu);  ac[5] += bf2f(q0.z >> 16);
        ac[6] += bf2f(q0.w & 0xFFFFu);  ac[7] += bf2f(q0.w >> 16);
        ac[8] += bf2f(q1.x & 0xFFFFu);  ac[9] += bf2f(q1.x >> 16);
        ac[10] += bf2f(q1.y & 0xFFFFu); ac[11] += bf2f(q1.y >> 16);
        ac[12] += bf2f(q1.z & 0xFFFFu); ac[13] += bf2f(q1.z >> 16);
        ac[14] += bf2f(q1.w & 0xFFFFu); ac[15] += bf2f(q1.w >> 16);
    };
    auto gather = [&](int kt) {
        #pragma unroll
        for (int i = 0; i < 16; ++i) ac[i] = 0.f;
        if (kt < 14) {
            const int doff = (kt & 1) * 32 + c * 8;
            const int seg = (kt >> 1) * N_NODES + n;
            const int beg = rp[seg], end = rp[seg + 1];
            int e = beg;
            while (e < end) {                       // 4-way unrolled, indep loads
                const int s0 = (int)csr16[e];
                int s1 = -1, s2 = -1, s3 = -1;
                if (e + 1 < end) s1 = (int)csr16[e + 1];
                if (e + 2 < end) s2 = (int)csr16[e + 2];
                if (e + 3 < end) s3 = (int)csr16[e + 3];
                accum(s0, doff);
                if (s1 >= 0) accum(s1, doff);
                if (s2 >= 0) accum(s2, doff);
                if (s3 >= 0) accum(s3, doff);
                e += 4;
            }
            sc = 1.f / (float)max(end - beg, 1);
        } else {                                    // root: identity read of h
            const int doff = (kt - 14) * 32 + c * 8;
            accum(n, doff);
            sc = 1.f;
        }
    };

    // ---- write gathered regs as swizzled bf16 A-tile granules ----
    auto writeA = [&]() {
        uint w[8];
        #pragma unroll
        for (int i = 0; i < 8; ++i) w[i] = pack2(ac[2 * i] * sc, ac[2 * i + 1] * sc);
        ushort* base = &u.s.a[nl * 64];
        const int s0 = (2 * c) ^ (nl & 7);
        const int s1 = (2 * c + 1) ^ (nl & 7);
        *(uint4*)&base[s0 * 8] = make_uint4(w[0], w[1], w[2], w[3]);
        *(uint4*)&base[s1 * 8] = make_uint4(w[4], w[5], w[6], w[7]);
    };

    f32x4v acc[2][4];
    #pragma unroll
    for (int fm = 0; fm < 2; ++fm)
        #pragma unroll
        for (int fn = 0; fn < 4; ++fn)
            acc[fm][fn] = (f32x4v){0.f, 0.f, 0.f, 0.f};

    auto mfma_step = [&](int buf) {
        #pragma unroll
        for (int kh = 0; kh < 2; ++kh) {
            bf16x8v af[2], bfr[4];
            #pragma unroll
            for (int fm = 0; fm < 2; ++fm) {
                const int rowa = wrow * 32 + fm * 16 + l15;
                const int sa = (kh * 4 + lh) ^ (rowa & 7);
                af[fm] = *(const bf16x8v*)&u.s.a[rowa * 64 + sa * 8];
            }
            #pragma unroll
            for (int fn = 0; fn < 4; ++fn) {
                const int rowb = wcol * 64 + fn * 16 + l15;
                const int sb = (kh * 4 + lh) ^ (rowb & 7);
                bfr[fn] = *(const bf16x8v*)&u.s.b[buf][rowb * 64 + sb * 8];
            }
            #pragma unroll
            for (int fm = 0; fm < 2; ++fm)
                #pragma unroll
                for (int fn = 0; fn < 4; ++fn)
                    acc[fm][fn] = __builtin_amdgcn_mfma_f32_16x16x32_bf16(
                        af[fm], bfr[fn], acc[fm][fn], 0, 0, 0);
        }
    };

    // ---- pipeline ----
    stageB(0, 0);
    gather(0);
    #pragma unroll 1
    for (int kt = 0; kt < 16; ++kt) {
        const int cur = kt & 1;
        // drain B(cur) into LDS + gather(kt) into regs; sync (prev MFMA done)
        asm volatile("s_waitcnt vmcnt(0)\n\ts_barrier" ::: "memory");
        writeA();
        if (kt < 15) stageB(cur ^ 1, kt + 1);      // in flight across barrier
        asm volatile("s_waitcnt lgkmcnt(0)\n\ts_barrier" ::: "memory");
        if (kt < 15) gather(kt + 1);               // overlaps MFMA below
        mfma_step(cur);
    }
    __syncthreads();

    // ---- fused LayerNorm + ReLU epilogue ----
    #pragma unroll
    for (int fm = 0; fm < 2; ++fm) {
        const int rl = wrow * 32 + fm * 16 + lh * 4;
        #pragma unroll
        for (int fn = 0; fn < 4; ++fn) {
            const int cl = wcol * 64 + fn * 16 + l15;
            const float bi = sbi[cl];
            #pragma unroll
            for (int r = 0; r < 4; ++r)
                u.ep[(rl + r) * 132 + cl] = acc[fm][fn][r] + bi;
        }
    }
    __syncthreads();
    {
        const int r_loc = tid >> 2, cb = tid & 3;   // 4 threads per row
        const int row_g = row0 + r_loc;
        float v[32];
        float s = 0.f, sq = 0.f;
        #pragma unroll
        for (int q = 0; q < 8; ++q) {
            const float4 t4 = *(const float4*)&u.ep[r_loc * 132 + cb * 32 + q * 4];
            v[4 * q + 0] = t4.x; v[4 * q + 1] = t4.y;
            v[4 * q + 2] = t4.z; v[4 * q + 3] = t4.w;
            s += t4.x + t4.y + t4.z + t4.w;
            sq += t4.x * t4.x + t4.y * t4.y + t4.z * t4.z + t4.w * t4.w;
        }
        s += __shfl_xor(s, 1, 64); sq += __shfl_xor(sq, 1, 64);
        s += __shfl_xor(s, 2, 64); sq += __shfl_xor(sq, 2, 64);
        const float mean = s * (1.f / 128.f);
        const float var = sq * (1.f / 128.f) - mean * mean;
        const float rs = rsqrtf(var + LEPS);
        if (row_g < nrows) {
            uint o[16];
            #pragma unroll
            for (int q2 = 0; q2 < 16; ++q2) {
                const int c0 = cb * 32 + 2 * q2;
                const float va = fmaxf((v[2 * q2]     - mean) * rs * sg[c0]     + sbb[c0],     0.f);
                const float vb = fmaxf((v[2 * q2 + 1] - mean) * rs * sg[c0 + 1] + sbb[c0 + 1], 0.f);
                o[q2] = pack2(va, vb);
            }
            uint* op = out + (size_t)row_g * 64 + cb * 16;
            *(uint4*)(op + 0)  = make_uint4(o[0], o[1], o[2], o[3]);
            *(uint4*)(op + 4)  = make_uint4(o[4], o[5], o[6], o[7]);
            *(uint4*)(op + 8)  = make_uint4(o[8], o[9], o[10], o[11]);
            *(uint4*)(op + 12) = make_uint4(o[12], o[13], o[14], o[15]);
        }
    }
}

// ---------------- classifier: MFMA h@W1 + in-register LN/ReLU/W2-dot ----------
__global__ __launch_bounds__(256) void k_cls(const ushort* __restrict__ h16,
                                             const float* __restrict__ W1,   // [128][64]
                                             const float* __restrict__ b1,
                                             const float* __restrict__ lg,
                                             const float* __restrict__ lb,
                                             const float* __restrict__ W2,   // [64]
                                             const float* __restrict__ b2,
                                             float* __restrict__ outp, int nrows) {
    __shared__ ushort Bs[16 * 64 * 8];   // [k-granule g][col j'][8 bf16], 16 KB
    const int tid = threadIdx.x;
    #pragma unroll
    for (int i = 0; i < 8; ++i) {
        const int q = i * 256 + tid;     // 2048 float4 = 8192 f32
        const int k = q >> 4;            // 0..127
        const int j0 = (q & 15) * 4;
        const float4 w = *(const float4*)(W1 + (size_t)k * 64 + j0);
        const int gg = k >> 3, kp = k & 7;
        const int jx = (gg & 3) << 4;
        Bs[(gg * 64 + ((j0 + 0) ^ jx)) * 8 + kp] = (ushort)f2bf(w.x);
        Bs[(gg * 64 + ((j0 + 1) ^ jx)) * 8 + kp] = (ushort)f2bf(w.y);
        Bs[(gg * 64 + ((j0 + 2) ^ jx)) * 8 + kp] = (ushort)f2bf(w.z);
        Bs[(gg * 64 + ((j0 + 3) ^ jx)) * 8 + kp] = (ushort)f2bf(w.w);
    }
    const int lane = tid & 63, wid = tid >> 6;
    const int l15 = lane & 15, lh = lane >> 4;
    float lgv[4], lbv[4], w2v[4], b1v[4];
    #pragma unroll
    for (int fn = 0; fn < 4; ++fn) {
        const int col = fn * 16 + l15;
        lgv[fn] = lg[col]; lbv[fn] = lb[col]; w2v[fn] = W2[col]; b1v[fn] = b1[col];
    }
    const float b2v = b2[0];
    __syncthreads();

    const int row0 = blockIdx.x * 128;
    f32x4v acc[2][4];
    #pragma unroll
    for (int fm = 0; fm < 2; ++fm)
        #pragma unroll
        for (int fn = 0; fn < 4; ++fn)
            acc[fm][fn] = (f32x4v){0.f, 0.f, 0.f, 0.f};

    #pragma unroll
    for (int kk = 0; kk < 4; ++kk) {
        bf16x8v af[2], bfr[4];
        #pragma unroll
        for (int fm = 0; fm < 2; ++fm) {
            const int row = min(row0 + wid * 32 + fm * 16 + l15, nrows - 1);
            af[fm] = *(const bf16x8v*)(h16 + (size_t)row * 128 + kk * 32 + lh * 8);
        }
        #pragma unroll
        for (int fn = 0; fn < 4; ++fn) {
            const int gg = kk * 4 + lh;
            const int jc = fn * 16 + l15;
            bfr[fn] = *(const bf16x8v*)&Bs[(gg * 64 + (jc ^ ((gg & 3) << 4))) * 8];
        }
        #pragma unroll
        for (int fm = 0; fm < 2; ++fm)
            #pragma unroll
            for (int fn = 0; fn < 4; ++fn)
                acc[fm][fn] = __builtin_amdgcn_mfma_f32_16x16x32_bf16(
                    af[fm], bfr[fn], acc[fm][fn], 0, 0, 0);
    }

    #pragma unroll
    for (int fm = 0; fm < 2; ++fm)
        #pragma unroll
        for (int r = 0; r < 4; ++r) {
            float cv[4];
            float s = 0.f, sq = 0.f;
            #pragma unroll
            for (int fn = 0; fn < 4; ++fn) {
                cv[fn] = acc[fm][fn][r] + b1v[fn];
                s += cv[fn]; sq += cv[fn] * cv[fn];
            }
            s += __shfl_xor(s, 1, 64); sq += __shfl_xor(sq, 1, 64);
            s += __shfl_xor(s, 2, 64); sq += __shfl_xor(sq, 2, 64);
            s += __shfl_xor(s, 4, 64); sq += __shfl_xor(sq, 4, 64);
            s += __shfl_xor(s, 8, 64); sq += __shfl_xor(sq, 8, 64);
            const float mean = s * (1.f / 64.f);
            const float var = sq * (1.f / 64.f) - mean * mean;
            const float rs = rsqrtf(var + LEPS);
            float dot = 0.f;
            #pragma unroll
            for (int fn = 0; fn < 4; ++fn)
                dot += fmaxf((cv[fn] - mean) * rs * lgv[fn] + lbv[fn], 0.f) * w2v[fn];
            dot += __shfl_xor(dot, 1, 64);
            dot += __shfl_xor(dot, 2, 64);
            dot += __shfl_xor(dot, 4, 64);
            dot += __shfl_xor(dot, 8, 64);
            const int row = row0 + wid * 32 + fm * 16 + lh * 4 + r;
            if (l15 == 0 && row < nrows) outp[row] = dot + b2v;
        }
}

extern "C" void kernel_launch(void* const* d_in, const int* in_sizes, int n_in,
                              void* d_out, int out_size, void* d_ws, size_t ws_size,
                              hipStream_t stream) {
    const float* x      = (const float*)d_in[0];
    const int*   eidx   = (const int*)d_in[1];
    const int*   etype  = (const int*)d_in[2];
    const float* emb_W  = (const float*)d_in[3];
    const float* emb_b  = (const float*)d_in[4];
    const float* rel_W  = (const float*)d_in[5];
    const float* root_W = (const float*)d_in[6];
    const float* conv_b = (const float*)d_in[7];
    const float* ln_g   = (const float*)d_in[8];
    const float* ln_b   = (const float*)d_in[9];
    const float* cls_W1 = (const float*)d_in[10];
    const float* cls_b1 = (const float*)d_in[11];
    const float* cls_lg = (const float*)d_in[12];
    const float* cls_lb = (const float*)d_in[13];
    const float* cls_W2 = (const float*)d_in[14];
    const float* cls_b2 = (const float*)d_in[15];

    const int* srcv = eidx;
    const int* dstv = eidx + N_EDGES;

    // workspace layout (~38 MB)
    char* ws = (char*)d_ws;
    size_t off = 0;
    auto alloc = [&](size_t bytes) { void* p = ws + off; off += (bytes + 255) & ~(size_t)255; return p; };
    uint*   h0    = (uint*)alloc((size_t)N_NODES * 64 * 4);     // bf16 h, dword-packed
    uint*   h1    = (uint*)alloc((size_t)N_NODES * 64 * 4);
    int*    rp    = (int*)alloc((size_t)(NSEG + 1) * 4);
    int*    deg   = (int*)alloc((size_t)2 * NSEG * 4);          // deg | fill
    ushort* csr16 = (ushort*)alloc((size_t)N_EDGES * 2);
    ushort* Btb   = (ushort*)alloc((size_t)2 * 128 * 1024 * 2); // bf16 B^T per layer
    int*    bs    = (int*)alloc(8192);
    int*    bsE   = (int*)alloc(8192);
    int*    bs2   = (int*)alloc(1024);
    int*    fill  = deg + NSEG;
    (void)ws_size; (void)n_in; (void)in_sizes; (void)out_size;

    const int ZB = (NSEG + 255) / 256;            // 1641
    const int Z2 = (ZB + 255) / 256;              // 7
    const int FUSED_BLKS = (N_NODES + 63) / 64;   // 938

    k_bt<<<64, 256, 0, stream>>>(rel_W, root_W, Btb);
    k_embed<<<512, 256, 0, stream>>>(x, emb_W, emb_b, (ushort*)h0);
    k_zero<<<(2 * NSEG + 255) / 256, 256, 0, stream>>>(deg, 2 * NSEG);
    k_deg<<<1024, 256, 0, stream>>>(dstv, etype, deg);
    k_scan1<<<ZB, 256, 0, stream>>>(deg, rp, bs, NSEG);
    k_scan1<<<Z2, 256, 0, stream>>>(bs, bsE, bs2, ZB);
    k_scan2<<<1, 256, 0, stream>>>(bs2, Z2);
    k_scanadd<<<Z2, 256, 0, stream>>>(bsE, bs2, ZB, 0);
    k_scanadd<<<ZB, 256, 0, stream>>>(rp, bsE, NSEG, 1);
    k_scatter<<<1024, 256, 0, stream>>>(srcv, dstv, etype, rp, fill, csr16);

    for (int l = 0; l < 2; ++l) {
        const uint* hin = l ? h1 : h0;
        uint* hout = l ? h0 : h1;
        k_fused<<<FUSED_BLKS, 256, 0, stream>>>(
            hin, rp, csr16,
            Btb + (size_t)l * 131072,
            conv_b + l * 128, ln_g + l * 128, ln_b + l * 128,
            hout, N_NODES);
    }
    k_cls<<<469, 256, 0, stream>>>((const ushort*)h0, cls_W1, cls_b1, cls_lg, cls_lb,
                                   cls_W2, cls_b2, (float*)d_out, N_NODES);
}